// Round 8
// baseline (1139.216 us; speedup 1.0000x reference)
//
#include <hip/hip_runtime.h>

#define NPIX   65536
#define HB     128
#define EPSF   1e-6f
#define NCOMB  24              /* (img*4+b)*3+g */
#define ROWB   48              /* 16 px * 2B = 32B data + 16B pad (3 x 16B) */
#define MATB   (HB * ROWB)     /* 6144 B per matrix */
#define BUFB   (3 * MATB)      /* 18432 B per buffer set */
#define PPW    24576           /* parts u32 words per block: 3*4*2*2*8*64 */

typedef _Float16 half8  __attribute__((ext_vector_type(8)));
typedef __fp16   fp16x2 __attribute__((ext_vector_type(2)));
typedef float    f32x16 __attribute__((ext_vector_type(16)));
typedef float    f32x2  __attribute__((ext_vector_type(2)));

__device__ __forceinline__ unsigned pk2(float a, float b) {
    union { fp16x2 h; unsigned u; } cv;
    cv.h = __builtin_amdgcn_cvt_pkrtz(a, b);
    return cv.u;
}

/* ---------------- kernel 1: pipelined shared-field MFMA histogram -----
 * Per (img,b): 3 fields d_rg, d_rb, d_gb -> 3 K-matrices (sqrt(w) folded).
 * G0=K_rg^T K_rb, G1=K_rg^T K_gb, G2=K_rb^T K_gb (bin-flips cancel in
 * norms+Hellinger).  Block=(img,b,chunk), 256 thr / 4 waves; LDS 36864B
 * -> 4 blocks/CU (4 waves/SIMD).  16-px regions, double-buffered LDS,
 * one barrier per region:
 *   body = { scalars[r+1]; prefetch loads[r+2]; gen[r+1]->buf(~p)
 *            || MFMA[r]<-buf(p) } ; barrier
 * Gen: lane owns px pair (lane&7) and row-group (lane>>3); rows
 * rbase=wave*8+q, stride 32 (4 steps).  ROWB=48 (12 words): lanes 0..7 hit
 * bank-quads {0,12,24,4,16,28,8,20} = all 32 banks -> conflict-free b128.
 * Epilogue: f16-pair packed parts (arbitrary but consistent layout --
 * norms+Hellinger are permutation-invariant). */
__global__ __launch_bounds__(256, 4) void hist_mfma(
    const float* __restrict__ pred, const float* __restrict__ tgt,
    unsigned* __restrict__ parts, int nchunk)
{
    __shared__ char smat[2 * BUFB];               /* 36864 B */

    const int t    = threadIdx.x;
    const int lane = t & 63;
    const int wave = t >> 6;
    const int chunk = blockIdx.x % nchunk;
    const int ib    = blockIdx.x / nchunk;        /* img*4 + b */
    const int b     = ib & 3;
    const int img   = ib >> 2;
    const int kchunk = NPIX / nchunk;
    const int nreg   = kchunk >> 4;               /* 16-px regions, even */

    const float* __restrict__ base = (img ? tgt : pred) + (size_t)b * 3 * NPIX;
    const float* __restrict__ Rp = base;
    const float* __restrict__ Gp = base + NPIX;
    const float* __restrict__ Bp = base + 2 * NPIX;

    /* gen role */
    const int   p2      = lane & 7;               /* px pair index (0..7) */
    const int   q       = lane >> 3;              /* row group (0..7) */
    const int   rbase   = wave * 8 + q;           /* 0..31 */
    const float MU0     = (float)rbase * (300.0f / 127.0f) - 150.0f;
    const float MUSTEP  = 32.0f * (300.0f / 127.0f);
    char* genp0 = smat + rbase * ROWB + p2 * 4;
    char* genp1 = genp0 + BUFB;

    /* mfma role */
    const int ti2 = wave >> 1;
    const int tj2 = wave & 1;

    f32x16 acc[3][2][2];
#pragma unroll
    for (int g = 0; g < 3; ++g)
#pragma unroll
        for (int i = 0; i < 2; ++i)
#pragma unroll
            for (int j = 0; j < 2; ++j)
#pragma unroll
                for (int r = 0; r < 16; ++r) acc[g][i][j][r] = 0.0f;

    const int n0 = chunk * kchunk;

    f32x2 Ra, Ga, Ba, Rb, Gb, Bb;                 /* load ping-pong */
    f32x2 ddrg, ddrb, ddgb, rw2;                  /* current scalars */

    auto issue_ld = [&](int reg, f32x2& R, f32x2& G, f32x2& B) {
        const int n = n0 + reg * 16 + 2 * p2;
        R = *reinterpret_cast<const f32x2*>(Rp + n);
        G = *reinterpret_cast<const f32x2*>(Gp + n);
        B = *reinterpret_cast<const f32x2*>(Bp + n);
    };

    auto scalars = [&](f32x2 R, f32x2 G, f32x2 B) {
        const float C = 34.65735902799726547086f;   /* 50 * ln2 */
        float r0 = fminf(fmaxf(R.x, 0.0f), 1.0f);
        float r1 = fminf(fmaxf(R.y, 0.0f), 1.0f);
        float g0 = fminf(fmaxf(G.x, 0.0f), 1.0f);
        float g1 = fminf(fmaxf(G.y, 0.0f), 1.0f);
        float b0 = fminf(fmaxf(B.x, 0.0f), 1.0f);
        float b1 = fminf(fmaxf(B.y, 0.0f), 1.0f);
        float lr0 = __builtin_amdgcn_logf(r0 + EPSF);
        float lr1 = __builtin_amdgcn_logf(r1 + EPSF);
        float lg0 = __builtin_amdgcn_logf(g0 + EPSF);
        float lg1 = __builtin_amdgcn_logf(g1 + EPSF);
        float lb0 = __builtin_amdgcn_logf(b0 + EPSF);
        float lb1 = __builtin_amdgcn_logf(b1 + EPSF);
        ddrg.x = (lr0 - lg0) * C;  ddrg.y = (lr1 - lg1) * C;
        ddrb.x = (lr0 - lb0) * C;  ddrb.y = (lr1 - lb1) * C;
        ddgb.x = (lg0 - lb0) * C;  ddgb.y = (lg1 - lb1) * C;
        const float s0 = __builtin_fmaf(r0, r0,
                          __builtin_fmaf(g0, g0,
                           __builtin_fmaf(b0, b0, EPSF)));
        const float s1 = __builtin_fmaf(r1, r1,
                          __builtin_fmaf(g1, g1,
                           __builtin_fmaf(b1, b1, EPSF)));
        rw2.x = __builtin_amdgcn_sqrtf(__builtin_amdgcn_sqrtf(s0));
        rw2.y = __builtin_amdgcn_sqrtf(__builtin_amdgcn_sqrtf(s1));
    };

    auto gen = [&](char* bp) {
#pragma unroll
        for (int mat = 0; mat < 3; ++mat) {
            const f32x2 dd = (mat == 0) ? ddrg : (mat == 1) ? ddrb : ddgb;
            float m = MU0;
#pragma unroll
            for (int s = 0; s < 4; ++s) {          /* rows rbase + 32*s */
                const float ex = dd.x - m, ey = dd.y - m;
                const float tx = __builtin_fmaf(ex, ex, 1.0f);
                const float ty = __builtin_fmaf(ey, ey, 1.0f);
                const float vx = __builtin_amdgcn_rcpf(tx) * rw2.x;
                const float vy = __builtin_amdgcn_rcpf(ty) * rw2.y;
                *reinterpret_cast<unsigned*>(bp + mat * MATB + s * 32 * ROWB)
                    = pk2(vx, vy);
                m += MUSTEP;
            }
        }
    };

    auto do_mfma = [&](const char* mp) {
        const int koff = (lane >> 5) << 4;        /* 0 or 16 bytes */
        const int r0 = ti2 * 64 + (lane & 31);
        const int c0 = tj2 * 64 + (lane & 31);
        half8 a0 = *reinterpret_cast<const half8*>(mp + 0 * MATB + r0 * ROWB + koff);
        half8 a1 = *reinterpret_cast<const half8*>(mp + 0 * MATB + (r0 + 32) * ROWB + koff);
        half8 p0 = *reinterpret_cast<const half8*>(mp + 1 * MATB + c0 * ROWB + koff);
        half8 p1 = *reinterpret_cast<const half8*>(mp + 1 * MATB + (c0 + 32) * ROWB + koff);
        acc[0][0][0] = __builtin_amdgcn_mfma_f32_32x32x16_f16(a0, p0, acc[0][0][0], 0, 0, 0);
        acc[0][0][1] = __builtin_amdgcn_mfma_f32_32x32x16_f16(a0, p1, acc[0][0][1], 0, 0, 0);
        acc[0][1][0] = __builtin_amdgcn_mfma_f32_32x32x16_f16(a1, p0, acc[0][1][0], 0, 0, 0);
        acc[0][1][1] = __builtin_amdgcn_mfma_f32_32x32x16_f16(a1, p1, acc[0][1][1], 0, 0, 0);
        half8 q0 = *reinterpret_cast<const half8*>(mp + 2 * MATB + c0 * ROWB + koff);
        half8 q1 = *reinterpret_cast<const half8*>(mp + 2 * MATB + (c0 + 32) * ROWB + koff);
        acc[1][0][0] = __builtin_amdgcn_mfma_f32_32x32x16_f16(a0, q0, acc[1][0][0], 0, 0, 0);
        acc[1][0][1] = __builtin_amdgcn_mfma_f32_32x32x16_f16(a0, q1, acc[1][0][1], 0, 0, 0);
        acc[1][1][0] = __builtin_amdgcn_mfma_f32_32x32x16_f16(a1, q0, acc[1][1][0], 0, 0, 0);
        acc[1][1][1] = __builtin_amdgcn_mfma_f32_32x32x16_f16(a1, q1, acc[1][1][1], 0, 0, 0);
        half8 bb0 = *reinterpret_cast<const half8*>(mp + 1 * MATB + r0 * ROWB + koff);
        half8 bb1 = *reinterpret_cast<const half8*>(mp + 1 * MATB + (r0 + 32) * ROWB + koff);
        acc[2][0][0] = __builtin_amdgcn_mfma_f32_32x32x16_f16(bb0, q0, acc[2][0][0], 0, 0, 0);
        acc[2][0][1] = __builtin_amdgcn_mfma_f32_32x32x16_f16(bb0, q1, acc[2][0][1], 0, 0, 0);
        acc[2][1][0] = __builtin_amdgcn_mfma_f32_32x32x16_f16(bb1, q0, acc[2][1][0], 0, 0, 0);
        acc[2][1][1] = __builtin_amdgcn_mfma_f32_32x32x16_f16(bb1, q1, acc[2][1][1], 0, 0, 0);
    };

    /* prologue: gen region 0 into buf0 */
    issue_ld(0, Ra, Ga, Ba);
    scalars(Ra, Ga, Ba);
    gen(genp0);
    issue_ld(1, Rb, Gb, Bb);
    __syncthreads();

    for (int rg = 0; rg < nreg; rg += 2) {
        /* body A: MFMA reg rg (buf0) || gen reg rg+1 -> buf1 */
        scalars(Rb, Gb, Bb);
        issue_ld(min(rg + 2, nreg - 1), Ra, Ga, Ba);
        gen(genp1);
        do_mfma(smat);
        __syncthreads();
        /* body B: MFMA reg rg+1 (buf1) || gen reg rg+2 -> buf0 */
        scalars(Ra, Ga, Ba);
        issue_ld(min(rg + 3, nreg - 1), Rb, Gb, Bb);
        if (rg + 2 < nreg) gen(genp0);
        do_mfma(smat + BUFB);
        __syncthreads();
    }

    /* ---- epilogue: pack f16 pairs (r,r+1), coalesced u32 stores.
     * Layout: word = (((g*4+wave)*2+i2)*2+j2)*8*64 + rh*64 + lane.
     * Any bijection is valid: norms + Hellinger are permutation-invariant
     * and pred/target use the identical mapping. */
    unsigned* pb0 = parts + (size_t)blockIdx.x * PPW;
#pragma unroll
    for (int g = 0; g < 3; ++g)
#pragma unroll
        for (int i2 = 0; i2 < 2; ++i2)
#pragma unroll
            for (int j2 = 0; j2 < 2; ++j2) {
                unsigned* wp = pb0
                    + (size_t)((((g * 4 + wave) * 2 + i2) * 2 + j2) * 8) * 64
                    + lane;
#pragma unroll
                for (int rh = 0; rh < 8; ++rh)
                    wp[rh * 64] = pk2(acc[g][i2][j2][2 * rh],
                                      acc[g][i2][j2][2 * rh + 1]);
            }
}

/* ------- kernel 2: reduce f16-pair partials + fused norm sums --------- */
__global__ __launch_bounds__(256) void reduce_norms(
    const unsigned* __restrict__ parts, float* __restrict__ hist,
    float* __restrict__ norms, int nchunk)
{
    const int i    = blockIdx.x * 256 + threadIdx.x;  /* pair idx < 196608 */
    const int comb = i >> 13;                         /* /8192, block-uniform */
    const int rest = i & 8191;
    const int ib   = comb / 3;
    const int g    = comb % 3;
    const unsigned* p = parts + (size_t)(ib * nchunk) * PPW + g * 8192 + rest;
    float s0 = 0.0f, s1 = 0.0f;
    for (int k = 0; k < nchunk; ++k) {
        union { unsigned u; fp16x2 h; } cv;
        cv.u = p[(size_t)k * PPW];
        s0 += (float)cv.h.x;
        s1 += (float)cv.h.y;
    }
    f32x2 o; o.x = s0; o.y = s1;
    *reinterpret_cast<f32x2*>(hist + 2 * (size_t)i) = o;
    /* block partial sum -> norms[ib] (ib uniform per block) */
    float s = s0 + s1;
    for (int o2 = 32; o2 > 0; o2 >>= 1) s += __shfl_down(s, o2, 64);
    __shared__ float wsum[4];
    if ((threadIdx.x & 63) == 0) wsum[threadIdx.x >> 6] = s;
    __syncthreads();
    if (threadIdx.x == 0)
        atomicAdd(&norms[ib], wsum[0] + wsum[1] + wsum[2] + wsum[3]);
}

/* ---------------- kernel 3: Hellinger sum ----------------------------- */
__global__ __launch_bounds__(256) void loss_k(
    const float* __restrict__ hist, const float* __restrict__ norms,
    float* __restrict__ acc)
{
    const int i  = blockIdx.x * 256 + threadIdx.x;  /* 0..196608, exact grid */
    const int bb = i / (3 * HB * HB);
    const float rp = __builtin_amdgcn_rcpf(norms[bb] + EPSF);
    const float rt = __builtin_amdgcn_rcpf(norms[4 + bb] + EPSF);
    const float p  = hist[i];
    const float tt = hist[12 * HB * HB + i];
    const float d  = __builtin_amdgcn_sqrtf(tt * rt)
                   - __builtin_amdgcn_sqrtf(p * rp);
    float s = d * d;
    for (int o = 32; o > 0; o >>= 1) s += __shfl_down(s, o, 64);
    __shared__ float wsum[4];
    if ((threadIdx.x & 63) == 0) wsum[threadIdx.x >> 6] = s;
    __syncthreads();
    if (threadIdx.x == 0) atomicAdd(acc, wsum[0] + wsum[1] + wsum[2] + wsum[3]);
}

/* ---------------- kernel 4: final scalar ------------------------------ */
__global__ void final_k(const float* __restrict__ acc, float* __restrict__ out)
{
    out[0] = __builtin_amdgcn_sqrtf(acc[0]) * 0.70710678118654752440f * 0.25f;
}

extern "C" void kernel_launch(void* const* d_in, const int* in_sizes, int n_in,
                              void* d_out, int out_size, void* d_ws, size_t ws_size,
                              hipStream_t stream)
{
    const float* pred = (const float*)d_in[0];
    const float* tgt  = (const float*)d_in[1];
    float* ws  = (float*)d_ws;
    float* out = (float*)d_out;

    float*    hist  = ws;             /* 24*16384 = 393216 floats          */
    float*    norms = ws + 393216;    /* 8 floats                          */
    float*    acc   = ws + 393224;    /* 1 float                           */
    unsigned* parts = (unsigned*)(ws + 393232); /* 8*nchunk*PPW u32        */

    /* largest chunk count whose parts buffer fits the workspace */
    int nchunk = 128;
    while (nchunk > 1) {
        const size_t need =
            (393232 + (size_t)8 * nchunk * PPW) * sizeof(float);
        if (need <= ws_size) break;
        nchunk >>= 1;
    }

    (void)hipMemsetAsync(norms, 0, 9 * sizeof(float), stream);  /* norms+acc */

    hist_mfma<<<8 * nchunk, 256, 0, stream>>>(pred, tgt, parts, nchunk);
    reduce_norms<<<NCOMB * HB * HB / 2 / 256, 256, 0, stream>>>(parts, hist,
                                                                norms, nchunk);
    loss_k<<<(4 * 3 * HB * HB) / 256, 256, 0, stream>>>(hist, norms, acc);
    final_k<<<1, 1, 0, stream>>>(acc, out);
}

// Round 9
// 120.944 us; speedup vs baseline: 9.4194x; 9.4194x over previous
//
#include <hip/hip_runtime.h>

#define NPIX   65536
#define HB     128
#define EPSF   1e-6f
#define NCOMB  24              /* (img*4+b)*3+g */
#define ROWB   80              /* 32 px * 2B = 64B data + 16B pad (5 x 16B) */
#define MATB   (HB * ROWB)     /* 10240 B per matrix */
#define BUFB   (3 * MATB)      /* 30720 B per buffer set */
#define PPW    24576           /* parts u32 words per block: 3*4*2*2*8*64 */

typedef _Float16 half8  __attribute__((ext_vector_type(8)));
typedef __fp16   fp16x2 __attribute__((ext_vector_type(2)));
typedef float    f32x16 __attribute__((ext_vector_type(16)));
typedef float    f32x2  __attribute__((ext_vector_type(2)));

__device__ __forceinline__ unsigned pk2(float a, float b) {
    union { fp16x2 h; unsigned u; } cv;
    cv.h = __builtin_amdgcn_cvt_pkrtz(a, b);
    return cv.u;
}

/* ---------------- kernel 1: pipelined shared-field MFMA histogram -----
 * Per (img,b): 3 fields d_rg, d_rb, d_gb -> 3 K-matrices (sqrt(w) folded).
 * G0=K_rg^T K_rb, G1=K_rg^T K_gb, G2=K_rb^T K_gb (bin-flips cancel in
 * norms+Hellinger).  Block=(img,b,chunk), 256 thr / 4 waves, 2 blocks/CU
 * (acc=192 f32 -> launch_bounds(256,2); (256,4) spills, round-8 lesson).
 * 32-px regions, double-buffered LDS, one barrier per region.  Body is
 * SLICE-INTERLEAVED so each wave alternates VALU-gen and MFMA clusters:
 *   {gen mat0 || 4 MFMA} {gen mat1 || 8 MFMA} {gen mat2 || 12 MFMA}
 * with s_setprio(1) around MFMA clusters (T5).  ROWB=80 keeps b128 reads
 * conflict-free.  Epilogue: f16-pair packed parts (permutation-invariant
 * layout; validated round 8, absmax 0.0). */
__global__ __launch_bounds__(256, 2) void hist_mfma(
    const float* __restrict__ pred, const float* __restrict__ tgt,
    unsigned* __restrict__ parts, int nchunk)
{
    __shared__ char smat[2 * BUFB];               /* 61440 B */

    const int t    = threadIdx.x;
    const int lane = t & 63;
    const int wave = t >> 6;
    const int chunk = blockIdx.x % nchunk;
    const int ib    = blockIdx.x / nchunk;        /* img*4 + b */
    const int b     = ib & 3;
    const int img   = ib >> 2;
    const int kchunk = NPIX / nchunk;
    const int nreg   = kchunk >> 5;               /* 32-px regions, even */

    const float* __restrict__ base = (img ? tgt : pred) + (size_t)b * 3 * NPIX;
    const float* __restrict__ Rp = base;
    const float* __restrict__ Gp = base + NPIX;
    const float* __restrict__ Bp = base + 2 * NPIX;

    /* gen role */
    const int   i16     = lane & 15;              /* px pair index */
    const int   r4      = lane >> 4;              /* row within 16-group */
    const int   rowbase = wave * 4 + r4;          /* 0..15 */
    const float MU0     = (float)rowbase * (300.0f / 127.0f) - 150.0f;
    const float MUSTEP  = 16.0f * (300.0f / 127.0f);
    char* genp0 = smat + rowbase * ROWB + i16 * 4;
    char* genp1 = genp0 + BUFB;

    /* mfma role */
    const int ti2 = wave >> 1;
    const int tj2 = wave & 1;

    f32x16 acc[3][2][2];
#pragma unroll
    for (int g = 0; g < 3; ++g)
#pragma unroll
        for (int i = 0; i < 2; ++i)
#pragma unroll
            for (int j = 0; j < 2; ++j)
#pragma unroll
                for (int r = 0; r < 16; ++r) acc[g][i][j][r] = 0.0f;

    const int n0 = chunk * kchunk;

    f32x2 Ra, Ga, Ba, Rb, Gb, Bb;                 /* load ping-pong */
    f32x2 ddrg, ddrb, ddgb, rw2;                  /* current scalars */

    auto issue_ld = [&](int reg, f32x2& R, f32x2& G, f32x2& B) {
        const int n = n0 + reg * 32 + 2 * i16;
        R = *reinterpret_cast<const f32x2*>(Rp + n);
        G = *reinterpret_cast<const f32x2*>(Gp + n);
        B = *reinterpret_cast<const f32x2*>(Bp + n);
    };

    auto scalars = [&](f32x2 R, f32x2 G, f32x2 B) {
        const float C = 34.65735902799726547086f;   /* 50 * ln2 */
        float r0 = fminf(fmaxf(R.x, 0.0f), 1.0f);
        float r1 = fminf(fmaxf(R.y, 0.0f), 1.0f);
        float g0 = fminf(fmaxf(G.x, 0.0f), 1.0f);
        float g1 = fminf(fmaxf(G.y, 0.0f), 1.0f);
        float b0 = fminf(fmaxf(B.x, 0.0f), 1.0f);
        float b1 = fminf(fmaxf(B.y, 0.0f), 1.0f);
        float lr0 = __builtin_amdgcn_logf(r0 + EPSF);
        float lr1 = __builtin_amdgcn_logf(r1 + EPSF);
        float lg0 = __builtin_amdgcn_logf(g0 + EPSF);
        float lg1 = __builtin_amdgcn_logf(g1 + EPSF);
        float lb0 = __builtin_amdgcn_logf(b0 + EPSF);
        float lb1 = __builtin_amdgcn_logf(b1 + EPSF);
        ddrg.x = (lr0 - lg0) * C;  ddrg.y = (lr1 - lg1) * C;
        ddrb.x = (lr0 - lb0) * C;  ddrb.y = (lr1 - lb1) * C;
        ddgb.x = (lg0 - lb0) * C;  ddgb.y = (lg1 - lb1) * C;
        const float s0 = __builtin_fmaf(r0, r0,
                          __builtin_fmaf(g0, g0,
                           __builtin_fmaf(b0, b0, EPSF)));
        const float s1 = __builtin_fmaf(r1, r1,
                          __builtin_fmaf(g1, g1,
                           __builtin_fmaf(b1, b1, EPSF)));
        rw2.x = __builtin_amdgcn_sqrtf(__builtin_amdgcn_sqrtf(s0));
        rw2.y = __builtin_amdgcn_sqrtf(__builtin_amdgcn_sqrtf(s1));
    };

    auto gen_mat = [&](char* bp, int mat, f32x2 dd) {
        float m = MU0;
#pragma unroll
        for (int s = 0; s < 8; ++s) {              /* rows rowbase + 16*s */
            const float ex = dd.x - m, ey = dd.y - m;
            const float tx = __builtin_fmaf(ex, ex, 1.0f);
            const float ty = __builtin_fmaf(ey, ey, 1.0f);
            const float vx = __builtin_amdgcn_rcpf(tx) * rw2.x;
            const float vy = __builtin_amdgcn_rcpf(ty) * rw2.y;
            *reinterpret_cast<unsigned*>(bp + mat * MATB + s * 16 * ROWB)
                = pk2(vx, vy);
            m += MUSTEP;
        }
    };

    auto rd = [&](const char* mp, int matid, int row, int koff) -> half8 {
        return *reinterpret_cast<const half8*>(mp + matid * MATB
                                               + row * ROWB + koff);
    };

    /* interleaved region body: read buf mp, optionally gen next into gp */
    auto body = [&](const char* mp, char* gp, bool dogen) {
        const int kbase = (lane >> 5) << 4;       /* 0 or 16 bytes */
        const int r0 = ti2 * 64 + (lane & 31);
        const int c0 = tj2 * 64 + (lane & 31);

        /* ---- slice 0: gen mat0 || G0 @ k0=0 ---- */
        if (dogen) gen_mat(gp, 0, ddrg);
        {
            half8 a0 = rd(mp, 0, r0,      kbase);
            half8 a1 = rd(mp, 0, r0 + 32, kbase);
            half8 p0 = rd(mp, 1, c0,      kbase);
            half8 p1 = rd(mp, 1, c0 + 32, kbase);
            __builtin_amdgcn_s_setprio(1);
            acc[0][0][0] = __builtin_amdgcn_mfma_f32_32x32x16_f16(a0, p0, acc[0][0][0], 0, 0, 0);
            acc[0][0][1] = __builtin_amdgcn_mfma_f32_32x32x16_f16(a0, p1, acc[0][0][1], 0, 0, 0);
            acc[0][1][0] = __builtin_amdgcn_mfma_f32_32x32x16_f16(a1, p0, acc[0][1][0], 0, 0, 0);
            acc[0][1][1] = __builtin_amdgcn_mfma_f32_32x32x16_f16(a1, p1, acc[0][1][1], 0, 0, 0);
            __builtin_amdgcn_s_setprio(0);

            /* ---- slice 1: gen mat1 || G1,G2 @ k0=0 ---- */
            if (dogen) gen_mat(gp, 1, ddrb);
            half8 q0  = rd(mp, 2, c0,      kbase);
            half8 q1  = rd(mp, 2, c0 + 32, kbase);
            half8 bb0 = rd(mp, 1, r0,      kbase);
            half8 bb1 = rd(mp, 1, r0 + 32, kbase);
            __builtin_amdgcn_s_setprio(1);
            acc[1][0][0] = __builtin_amdgcn_mfma_f32_32x32x16_f16(a0, q0, acc[1][0][0], 0, 0, 0);
            acc[1][0][1] = __builtin_amdgcn_mfma_f32_32x32x16_f16(a0, q1, acc[1][0][1], 0, 0, 0);
            acc[1][1][0] = __builtin_amdgcn_mfma_f32_32x32x16_f16(a1, q0, acc[1][1][0], 0, 0, 0);
            acc[1][1][1] = __builtin_amdgcn_mfma_f32_32x32x16_f16(a1, q1, acc[1][1][1], 0, 0, 0);
            acc[2][0][0] = __builtin_amdgcn_mfma_f32_32x32x16_f16(bb0, q0, acc[2][0][0], 0, 0, 0);
            acc[2][0][1] = __builtin_amdgcn_mfma_f32_32x32x16_f16(bb0, q1, acc[2][0][1], 0, 0, 0);
            acc[2][1][0] = __builtin_amdgcn_mfma_f32_32x32x16_f16(bb1, q0, acc[2][1][0], 0, 0, 0);
            acc[2][1][1] = __builtin_amdgcn_mfma_f32_32x32x16_f16(bb1, q1, acc[2][1][1], 0, 0, 0);
            __builtin_amdgcn_s_setprio(0);
        }

        /* ---- slice 2: gen mat2 || all 12 @ k0=1 ---- */
        if (dogen) gen_mat(gp, 2, ddgb);
        {
            const int k1 = 32 + kbase;
            half8 a0  = rd(mp, 0, r0,      k1);
            half8 a1  = rd(mp, 0, r0 + 32, k1);
            half8 p0  = rd(mp, 1, c0,      k1);
            half8 p1  = rd(mp, 1, c0 + 32, k1);
            half8 q0  = rd(mp, 2, c0,      k1);
            half8 q1  = rd(mp, 2, c0 + 32, k1);
            half8 bb0 = rd(mp, 1, r0,      k1);
            half8 bb1 = rd(mp, 1, r0 + 32, k1);
            __builtin_amdgcn_s_setprio(1);
            acc[0][0][0] = __builtin_amdgcn_mfma_f32_32x32x16_f16(a0, p0, acc[0][0][0], 0, 0, 0);
            acc[0][0][1] = __builtin_amdgcn_mfma_f32_32x32x16_f16(a0, p1, acc[0][0][1], 0, 0, 0);
            acc[0][1][0] = __builtin_amdgcn_mfma_f32_32x32x16_f16(a1, p0, acc[0][1][0], 0, 0, 0);
            acc[0][1][1] = __builtin_amdgcn_mfma_f32_32x32x16_f16(a1, p1, acc[0][1][1], 0, 0, 0);
            acc[1][0][0] = __builtin_amdgcn_mfma_f32_32x32x16_f16(a0, q0, acc[1][0][0], 0, 0, 0);
            acc[1][0][1] = __builtin_amdgcn_mfma_f32_32x32x16_f16(a0, q1, acc[1][0][1], 0, 0, 0);
            acc[1][1][0] = __builtin_amdgcn_mfma_f32_32x32x16_f16(a1, q0, acc[1][1][0], 0, 0, 0);
            acc[1][1][1] = __builtin_amdgcn_mfma_f32_32x32x16_f16(a1, q1, acc[1][1][1], 0, 0, 0);
            acc[2][0][0] = __builtin_amdgcn_mfma_f32_32x32x16_f16(bb0, q0, acc[2][0][0], 0, 0, 0);
            acc[2][0][1] = __builtin_amdgcn_mfma_f32_32x32x16_f16(bb0, q1, acc[2][0][1], 0, 0, 0);
            acc[2][1][0] = __builtin_amdgcn_mfma_f32_32x32x16_f16(bb1, q0, acc[2][1][0], 0, 0, 0);
            acc[2][1][1] = __builtin_amdgcn_mfma_f32_32x32x16_f16(bb1, q1, acc[2][1][1], 0, 0, 0);
            __builtin_amdgcn_s_setprio(0);
        }
    };

    /* prologue: gen region 0 into buf0 */
    issue_ld(0, Ra, Ga, Ba);
    scalars(Ra, Ga, Ba);
    gen_mat(genp0, 0, ddrg);
    gen_mat(genp0, 1, ddrb);
    gen_mat(genp0, 2, ddgb);
    issue_ld(1, Rb, Gb, Bb);
    __syncthreads();

    for (int rg = 0; rg < nreg; rg += 2) {
        /* body A: MFMA reg rg (buf0) || gen reg rg+1 -> buf1 */
        scalars(Rb, Gb, Bb);
        issue_ld(min(rg + 2, nreg - 1), Ra, Ga, Ba);
        body(smat, genp1, true);
        __syncthreads();
        /* body B: MFMA reg rg+1 (buf1) || gen reg rg+2 -> buf0 */
        scalars(Ra, Ga, Ba);
        issue_ld(min(rg + 3, nreg - 1), Rb, Gb, Bb);
        body(smat + BUFB, genp0, rg + 2 < nreg);
        __syncthreads();
    }

    /* ---- epilogue: pack f16 pairs, coalesced u32 stores.
     * Layout: word = (((g*4+wave)*2+i2)*2+j2)*8*64 + rh*64 + lane.
     * Any consistent bijection is valid (norms+Hellinger permutation-
     * invariant; pred/target use identical mapping).  Validated round 8. */
    unsigned* pb0 = parts + (size_t)blockIdx.x * PPW;
#pragma unroll
    for (int g = 0; g < 3; ++g)
#pragma unroll
        for (int i2 = 0; i2 < 2; ++i2)
#pragma unroll
            for (int j2 = 0; j2 < 2; ++j2) {
                unsigned* wp = pb0
                    + (size_t)((((g * 4 + wave) * 2 + i2) * 2 + j2) * 8) * 64
                    + lane;
#pragma unroll
                for (int rh = 0; rh < 8; ++rh)
                    wp[rh * 64] = pk2(acc[g][i2][j2][2 * rh],
                                      acc[g][i2][j2][2 * rh + 1]);
            }
}

/* ------- kernel 2: reduce f16-pair partials + fused norm sums --------- */
__global__ __launch_bounds__(256) void reduce_norms(
    const unsigned* __restrict__ parts, float* __restrict__ hist,
    float* __restrict__ norms, int nchunk)
{
    const int i    = blockIdx.x * 256 + threadIdx.x;  /* pair idx < 196608 */
    const int comb = i >> 13;                         /* /8192, block-uniform */
    const int rest = i & 8191;
    const int ib   = comb / 3;
    const int g    = comb % 3;
    const unsigned* p = parts + (size_t)(ib * nchunk) * PPW + g * 8192 + rest;
    float s0 = 0.0f, s1 = 0.0f;
    for (int k = 0; k < nchunk; ++k) {
        union { unsigned u; fp16x2 h; } cv;
        cv.u = p[(size_t)k * PPW];
        s0 += (float)cv.h.x;
        s1 += (float)cv.h.y;
    }
    f32x2 o; o.x = s0; o.y = s1;
    *reinterpret_cast<f32x2*>(hist + 2 * (size_t)i) = o;
    /* block partial sum -> norms[ib] (ib uniform per block) */
    float s = s0 + s1;
    for (int o2 = 32; o2 > 0; o2 >>= 1) s += __shfl_down(s, o2, 64);
    __shared__ float wsum[4];
    if ((threadIdx.x & 63) == 0) wsum[threadIdx.x >> 6] = s;
    __syncthreads();
    if (threadIdx.x == 0)
        atomicAdd(&norms[ib], wsum[0] + wsum[1] + wsum[2] + wsum[3]);
}

/* ---------------- kernel 3: Hellinger sum ----------------------------- */
__global__ __launch_bounds__(256) void loss_k(
    const float* __restrict__ hist, const float* __restrict__ norms,
    float* __restrict__ acc)
{
    const int i  = blockIdx.x * 256 + threadIdx.x;  /* 0..196608, exact grid */
    const int bb = i / (3 * HB * HB);
    const float rp = __builtin_amdgcn_rcpf(norms[bb] + EPSF);
    const float rt = __builtin_amdgcn_rcpf(norms[4 + bb] + EPSF);
    const float p  = hist[i];
    const float tt = hist[12 * HB * HB + i];
    const float d  = __builtin_amdgcn_sqrtf(tt * rt)
                   - __builtin_amdgcn_sqrtf(p * rp);
    float s = d * d;
    for (int o = 32; o > 0; o >>= 1) s += __shfl_down(s, o, 64);
    __shared__ float wsum[4];
    if ((threadIdx.x & 63) == 0) wsum[threadIdx.x >> 6] = s;
    __syncthreads();
    if (threadIdx.x == 0) atomicAdd(acc, wsum[0] + wsum[1] + wsum[2] + wsum[3]);
}

/* ---------------- kernel 4: final scalar ------------------------------ */
__global__ void final_k(const float* __restrict__ acc, float* __restrict__ out)
{
    out[0] = __builtin_amdgcn_sqrtf(acc[0]) * 0.70710678118654752440f * 0.25f;
}

extern "C" void kernel_launch(void* const* d_in, const int* in_sizes, int n_in,
                              void* d_out, int out_size, void* d_ws, size_t ws_size,
                              hipStream_t stream)
{
    const float* pred = (const float*)d_in[0];
    const float* tgt  = (const float*)d_in[1];
    float* ws  = (float*)d_ws;
    float* out = (float*)d_out;

    float*    hist  = ws;             /* 24*16384 = 393216 floats          */
    float*    norms = ws + 393216;    /* 8 floats                          */
    float*    acc   = ws + 393224;    /* 1 float                           */
    unsigned* parts = (unsigned*)(ws + 393232); /* 8*nchunk*PPW u32        */

    /* largest chunk count whose parts buffer fits (64 fills 2 blocks/CU) */
    int nchunk = 64;
    while (nchunk > 1) {
        const size_t need =
            (393232 + (size_t)8 * nchunk * PPW) * sizeof(float);
        if (need <= ws_size) break;
        nchunk >>= 1;
    }

    (void)hipMemsetAsync(norms, 0, 9 * sizeof(float), stream);  /* norms+acc */

    hist_mfma<<<8 * nchunk, 256, 0, stream>>>(pred, tgt, parts, nchunk);
    reduce_norms<<<NCOMB * HB * HB / 2 / 256, 256, 0, stream>>>(parts, hist,
                                                                norms, nchunk);
    loss_k<<<(4 * 3 * HB * HB) / 256, 256, 0, stream>>>(hist, norms, acc);
    final_k<<<1, 1, 0, stream>>>(acc, out);
}

// Round 10
// 99.460 us; speedup vs baseline: 11.4540x; 1.2160x over previous
//
#include <hip/hip_runtime.h>

#define NPIX   65536
#define HB     128
#define EPSF   1e-6f
#define ROWB   80              /* 32 px * 2B = 64B data + 16B pad (5 x 16B) */
#define MATB   (HB * ROWB)     /* 10240 B per matrix */
#define BUFB   (3 * MATB)      /* 30720 B per buffer set */
#define PPW    24576           /* parts u32 words per block: 3*4*2*2*8*64 */

typedef _Float16 half8  __attribute__((ext_vector_type(8)));
typedef __fp16   fp16x2 __attribute__((ext_vector_type(2)));
typedef float    f32x16 __attribute__((ext_vector_type(16)));
typedef float    f32x2  __attribute__((ext_vector_type(2)));

__device__ __forceinline__ unsigned pk2(float a, float b) {
    union { fp16x2 h; unsigned u; } cv;
    cv.h = __builtin_amdgcn_cvt_pkrtz(a, b);
    return cv.u;
}

/* ---------------- kernel 1: pipelined shared-field MFMA histogram -----
 * Per (img,b): 3 fields d_rg, d_rb, d_gb -> 3 K-matrices (sqrt(w) folded).
 * G0=K_rg^T K_rb, G1=K_rg^T K_gb, G2=K_rb^T K_gb (bin-flips cancel in
 * norms+Hellinger).  Block=(img,b,chunk), 256 thr / 4 waves, 2 blocks/CU
 * (acc=192 f32 -> launch_bounds(256,2); (256,4) spills, round-8 lesson).
 * 32-px regions, double-buffered LDS, one barrier per region, body
 * slice-interleaved (gen||MFMA) with s_setprio around MFMA clusters.
 * NEW (r10): block also reduces its own acc -> atomicAdd(norms[ib]), so
 * norms are ready before the fused reduce+loss kernel. */
__global__ __launch_bounds__(256, 2) void hist_mfma(
    const float* __restrict__ pred, const float* __restrict__ tgt,
    unsigned* __restrict__ parts, float* __restrict__ norms, int nchunk)
{
    __shared__ char smat[2 * BUFB];               /* 61440 B */

    const int t    = threadIdx.x;
    const int lane = t & 63;
    const int wave = t >> 6;
    const int chunk = blockIdx.x % nchunk;
    const int ib    = blockIdx.x / nchunk;        /* img*4 + b */
    const int b     = ib & 3;
    const int img   = ib >> 2;
    const int kchunk = NPIX / nchunk;
    const int nreg   = kchunk >> 5;               /* 32-px regions, even */

    const float* __restrict__ base = (img ? tgt : pred) + (size_t)b * 3 * NPIX;
    const float* __restrict__ Rp = base;
    const float* __restrict__ Gp = base + NPIX;
    const float* __restrict__ Bp = base + 2 * NPIX;

    /* gen role */
    const int   i16     = lane & 15;              /* px pair index */
    const int   r4      = lane >> 4;              /* row within 16-group */
    const int   rowbase = wave * 4 + r4;          /* 0..15 */
    const float MU0     = (float)rowbase * (300.0f / 127.0f) - 150.0f;
    const float MUSTEP  = 16.0f * (300.0f / 127.0f);
    char* genp0 = smat + rowbase * ROWB + i16 * 4;
    char* genp1 = genp0 + BUFB;

    /* mfma role */
    const int ti2 = wave >> 1;
    const int tj2 = wave & 1;

    f32x16 acc[3][2][2];
#pragma unroll
    for (int g = 0; g < 3; ++g)
#pragma unroll
        for (int i = 0; i < 2; ++i)
#pragma unroll
            for (int j = 0; j < 2; ++j)
#pragma unroll
                for (int r = 0; r < 16; ++r) acc[g][i][j][r] = 0.0f;

    const int n0 = chunk * kchunk;

    f32x2 Ra, Ga, Ba, Rb, Gb, Bb;                 /* load ping-pong */
    f32x2 ddrg, ddrb, ddgb, rw2;                  /* current scalars */

    auto issue_ld = [&](int reg, f32x2& R, f32x2& G, f32x2& B) {
        const int n = n0 + reg * 32 + 2 * i16;
        R = *reinterpret_cast<const f32x2*>(Rp + n);
        G = *reinterpret_cast<const f32x2*>(Gp + n);
        B = *reinterpret_cast<const f32x2*>(Bp + n);
    };

    auto scalars = [&](f32x2 R, f32x2 G, f32x2 B) {
        const float C = 34.65735902799726547086f;   /* 50 * ln2 */
        float r0 = fminf(fmaxf(R.x, 0.0f), 1.0f);
        float r1 = fminf(fmaxf(R.y, 0.0f), 1.0f);
        float g0 = fminf(fmaxf(G.x, 0.0f), 1.0f);
        float g1 = fminf(fmaxf(G.y, 0.0f), 1.0f);
        float b0 = fminf(fmaxf(B.x, 0.0f), 1.0f);
        float b1 = fminf(fmaxf(B.y, 0.0f), 1.0f);
        float lr0 = __builtin_amdgcn_logf(r0 + EPSF);
        float lr1 = __builtin_amdgcn_logf(r1 + EPSF);
        float lg0 = __builtin_amdgcn_logf(g0 + EPSF);
        float lg1 = __builtin_amdgcn_logf(g1 + EPSF);
        float lb0 = __builtin_amdgcn_logf(b0 + EPSF);
        float lb1 = __builtin_amdgcn_logf(b1 + EPSF);
        ddrg.x = (lr0 - lg0) * C;  ddrg.y = (lr1 - lg1) * C;
        ddrb.x = (lr0 - lb0) * C;  ddrb.y = (lr1 - lb1) * C;
        ddgb.x = (lg0 - lb0) * C;  ddgb.y = (lg1 - lb1) * C;
        const float s0 = __builtin_fmaf(r0, r0,
                          __builtin_fmaf(g0, g0,
                           __builtin_fmaf(b0, b0, EPSF)));
        const float s1 = __builtin_fmaf(r1, r1,
                          __builtin_fmaf(g1, g1,
                           __builtin_fmaf(b1, b1, EPSF)));
        rw2.x = __builtin_amdgcn_sqrtf(__builtin_amdgcn_sqrtf(s0));
        rw2.y = __builtin_amdgcn_sqrtf(__builtin_amdgcn_sqrtf(s1));
    };

    auto gen_mat = [&](char* bp, int mat, f32x2 dd) {
        float m = MU0;
#pragma unroll
        for (int s = 0; s < 8; ++s) {              /* rows rowbase + 16*s */
            const float ex = dd.x - m, ey = dd.y - m;
            const float tx = __builtin_fmaf(ex, ex, 1.0f);
            const float ty = __builtin_fmaf(ey, ey, 1.0f);
            const float vx = __builtin_amdgcn_rcpf(tx) * rw2.x;
            const float vy = __builtin_amdgcn_rcpf(ty) * rw2.y;
            *reinterpret_cast<unsigned*>(bp + mat * MATB + s * 16 * ROWB)
                = pk2(vx, vy);
            m += MUSTEP;
        }
    };

    auto rd = [&](const char* mp, int matid, int row, int koff) -> half8 {
        return *reinterpret_cast<const half8*>(mp + matid * MATB
                                               + row * ROWB + koff);
    };

    /* interleaved region body: read buf mp, optionally gen next into gp */
    auto body = [&](const char* mp, char* gp, bool dogen) {
        const int kbase = (lane >> 5) << 4;       /* 0 or 16 bytes */
        const int r0 = ti2 * 64 + (lane & 31);
        const int c0 = tj2 * 64 + (lane & 31);

        /* ---- slice 0: gen mat0 || G0 @ k0=0 ---- */
        if (dogen) gen_mat(gp, 0, ddrg);
        {
            half8 a0 = rd(mp, 0, r0,      kbase);
            half8 a1 = rd(mp, 0, r0 + 32, kbase);
            half8 p0 = rd(mp, 1, c0,      kbase);
            half8 p1 = rd(mp, 1, c0 + 32, kbase);
            __builtin_amdgcn_s_setprio(1);
            acc[0][0][0] = __builtin_amdgcn_mfma_f32_32x32x16_f16(a0, p0, acc[0][0][0], 0, 0, 0);
            acc[0][0][1] = __builtin_amdgcn_mfma_f32_32x32x16_f16(a0, p1, acc[0][0][1], 0, 0, 0);
            acc[0][1][0] = __builtin_amdgcn_mfma_f32_32x32x16_f16(a1, p0, acc[0][1][0], 0, 0, 0);
            acc[0][1][1] = __builtin_amdgcn_mfma_f32_32x32x16_f16(a1, p1, acc[0][1][1], 0, 0, 0);
            __builtin_amdgcn_s_setprio(0);

            /* ---- slice 1: gen mat1 || G1,G2 @ k0=0 ---- */
            if (dogen) gen_mat(gp, 1, ddrb);
            half8 q0  = rd(mp, 2, c0,      kbase);
            half8 q1  = rd(mp, 2, c0 + 32, kbase);
            half8 bb0 = rd(mp, 1, r0,      kbase);
            half8 bb1 = rd(mp, 1, r0 + 32, kbase);
            __builtin_amdgcn_s_setprio(1);
            acc[1][0][0] = __builtin_amdgcn_mfma_f32_32x32x16_f16(a0, q0, acc[1][0][0], 0, 0, 0);
            acc[1][0][1] = __builtin_amdgcn_mfma_f32_32x32x16_f16(a0, q1, acc[1][0][1], 0, 0, 0);
            acc[1][1][0] = __builtin_amdgcn_mfma_f32_32x32x16_f16(a1, q0, acc[1][1][0], 0, 0, 0);
            acc[1][1][1] = __builtin_amdgcn_mfma_f32_32x32x16_f16(a1, q1, acc[1][1][1], 0, 0, 0);
            acc[2][0][0] = __builtin_amdgcn_mfma_f32_32x32x16_f16(bb0, q0, acc[2][0][0], 0, 0, 0);
            acc[2][0][1] = __builtin_amdgcn_mfma_f32_32x32x16_f16(bb0, q1, acc[2][0][1], 0, 0, 0);
            acc[2][1][0] = __builtin_amdgcn_mfma_f32_32x32x16_f16(bb1, q0, acc[2][1][0], 0, 0, 0);
            acc[2][1][1] = __builtin_amdgcn_mfma_f32_32x32x16_f16(bb1, q1, acc[2][1][1], 0, 0, 0);
            __builtin_amdgcn_s_setprio(0);
        }

        /* ---- slice 2: gen mat2 || all 12 @ k0=1 ---- */
        if (dogen) gen_mat(gp, 2, ddgb);
        {
            const int k1 = 32 + kbase;
            half8 a0  = rd(mp, 0, r0,      k1);
            half8 a1  = rd(mp, 0, r0 + 32, k1);
            half8 p0  = rd(mp, 1, c0,      k1);
            half8 p1  = rd(mp, 1, c0 + 32, k1);
            half8 q0  = rd(mp, 2, c0,      k1);
            half8 q1  = rd(mp, 2, c0 + 32, k1);
            half8 bb0 = rd(mp, 1, r0,      k1);
            half8 bb1 = rd(mp, 1, r0 + 32, k1);
            __builtin_amdgcn_s_setprio(1);
            acc[0][0][0] = __builtin_amdgcn_mfma_f32_32x32x16_f16(a0, p0, acc[0][0][0], 0, 0, 0);
            acc[0][0][1] = __builtin_amdgcn_mfma_f32_32x32x16_f16(a0, p1, acc[0][0][1], 0, 0, 0);
            acc[0][1][0] = __builtin_amdgcn_mfma_f32_32x32x16_f16(a1, p0, acc[0][1][0], 0, 0, 0);
            acc[0][1][1] = __builtin_amdgcn_mfma_f32_32x32x16_f16(a1, p1, acc[0][1][1], 0, 0, 0);
            acc[1][0][0] = __builtin_amdgcn_mfma_f32_32x32x16_f16(a0, q0, acc[1][0][0], 0, 0, 0);
            acc[1][0][1] = __builtin_amdgcn_mfma_f32_32x32x16_f16(a0, q1, acc[1][0][1], 0, 0, 0);
            acc[1][1][0] = __builtin_amdgcn_mfma_f32_32x32x16_f16(a1, q0, acc[1][1][0], 0, 0, 0);
            acc[1][1][1] = __builtin_amdgcn_mfma_f32_32x32x16_f16(a1, q1, acc[1][1][1], 0, 0, 0);
            acc[2][0][0] = __builtin_amdgcn_mfma_f32_32x32x16_f16(bb0, q0, acc[2][0][0], 0, 0, 0);
            acc[2][0][1] = __builtin_amdgcn_mfma_f32_32x32x16_f16(bb0, q1, acc[2][0][1], 0, 0, 0);
            acc[2][1][0] = __builtin_amdgcn_mfma_f32_32x32x16_f16(bb1, q0, acc[2][1][0], 0, 0, 0);
            acc[2][1][1] = __builtin_amdgcn_mfma_f32_32x32x16_f16(bb1, q1, acc[2][1][1], 0, 0, 0);
            __builtin_amdgcn_s_setprio(0);
        }
    };

    /* prologue: gen region 0 into buf0 */
    issue_ld(0, Ra, Ga, Ba);
    scalars(Ra, Ga, Ba);
    gen_mat(genp0, 0, ddrg);
    gen_mat(genp0, 1, ddrb);
    gen_mat(genp0, 2, ddgb);
    issue_ld(1, Rb, Gb, Bb);
    __syncthreads();

    for (int rg = 0; rg < nreg; rg += 2) {
        /* body A: MFMA reg rg (buf0) || gen reg rg+1 -> buf1 */
        scalars(Rb, Gb, Bb);
        issue_ld(min(rg + 2, nreg - 1), Ra, Ga, Ba);
        body(smat, genp1, true);
        __syncthreads();
        /* body B: MFMA reg rg+1 (buf1) || gen reg rg+2 -> buf0 */
        scalars(Ra, Ga, Ba);
        issue_ld(min(rg + 3, nreg - 1), Rb, Gb, Bb);
        body(smat + BUFB, genp0, rg + 2 < nreg);
        __syncthreads();
    }

    /* ---- epilogue A: pack f16 pairs, coalesced u32 stores.
     * Layout: word = (((g*4+wave)*2+i2)*2+j2)*8*64 + rh*64 + lane.
     * Any consistent bijection is valid (norms+Hellinger permutation-
     * invariant; pred/target use identical mapping).  Validated round 8. */
    unsigned* pb0 = parts + (size_t)blockIdx.x * PPW;
    float blksum = 0.0f;
#pragma unroll
    for (int g = 0; g < 3; ++g)
#pragma unroll
        for (int i2 = 0; i2 < 2; ++i2)
#pragma unroll
            for (int j2 = 0; j2 < 2; ++j2) {
                unsigned* wp = pb0
                    + (size_t)((((g * 4 + wave) * 2 + i2) * 2 + j2) * 8) * 64
                    + lane;
#pragma unroll
                for (int rh = 0; rh < 8; ++rh) {
                    wp[rh * 64] = pk2(acc[g][i2][j2][2 * rh],
                                      acc[g][i2][j2][2 * rh + 1]);
                    blksum += acc[g][i2][j2][2 * rh]
                            + acc[g][i2][j2][2 * rh + 1];
                }
            }

    /* ---- epilogue B: block contribution to norms[ib] ---- */
    for (int o = 32; o > 0; o >>= 1) blksum += __shfl_down(blksum, o, 64);
    __shared__ float wsum[4];
    if (lane == 0) wsum[wave] = blksum;
    __syncthreads();
    if (t == 0)
        atomicAdd(&norms[ib], wsum[0] + wsum[1] + wsum[2] + wsum[3]);
}

/* ------- kernel 2: fused parts-reduce + Hellinger + loss --------------
 * Thread = one (b, g, pair-pos): sums 64 pred parts + 64 tgt parts
 * (8-way unrolled -> many outstanding loads), then sqrt-diff^2,
 * block-reduce, one atomicAdd.  norms already complete (kernel 1). */
__global__ __launch_bounds__(256) void reduce_loss(
    const unsigned* __restrict__ parts, const float* __restrict__ norms,
    float* __restrict__ acc, int nchunk)
{
    const int i      = blockIdx.x * 256 + threadIdx.x;  /* < 98304 */
    const int comb12 = i >> 13;                         /* block-uniform */
    const int rest   = i & 8191;
    const int b      = comb12 / 3;
    const int g      = comb12 % 3;
    const unsigned* pp = parts + (size_t)(b * nchunk) * PPW + g * 8192 + rest;
    const unsigned* pt = parts + (size_t)((4 + b) * nchunk) * PPW + g * 8192 + rest;

    float hp0 = 0.0f, hp1 = 0.0f, ht0 = 0.0f, ht1 = 0.0f;
    int k = 0;
    for (; k + 8 <= nchunk; k += 8) {
#pragma unroll
        for (int j = 0; j < 8; ++j) {
            union { unsigned u; fp16x2 h; } a, c;
            a.u = pp[(size_t)(k + j) * PPW];
            c.u = pt[(size_t)(k + j) * PPW];
            hp0 += (float)a.h.x;  hp1 += (float)a.h.y;
            ht0 += (float)c.h.x;  ht1 += (float)c.h.y;
        }
    }
    for (; k < nchunk; ++k) {
        union { unsigned u; fp16x2 h; } a, c;
        a.u = pp[(size_t)k * PPW];
        c.u = pt[(size_t)k * PPW];
        hp0 += (float)a.h.x;  hp1 += (float)a.h.y;
        ht0 += (float)c.h.x;  ht1 += (float)c.h.y;
    }

    const float rp = __builtin_amdgcn_rcpf(norms[b] + EPSF);
    const float rt = __builtin_amdgcn_rcpf(norms[4 + b] + EPSF);
    const float d0 = __builtin_amdgcn_sqrtf(ht0 * rt)
                   - __builtin_amdgcn_sqrtf(hp0 * rp);
    const float d1 = __builtin_amdgcn_sqrtf(ht1 * rt)
                   - __builtin_amdgcn_sqrtf(hp1 * rp);
    float s = __builtin_fmaf(d0, d0, d1 * d1);
    for (int o = 32; o > 0; o >>= 1) s += __shfl_down(s, o, 64);
    __shared__ float wsum[4];
    if ((threadIdx.x & 63) == 0) wsum[threadIdx.x >> 6] = s;
    __syncthreads();
    if (threadIdx.x == 0) atomicAdd(acc, wsum[0] + wsum[1] + wsum[2] + wsum[3]);
}

/* ---------------- kernel 3: final scalar ------------------------------ */
__global__ void final_k(const float* __restrict__ acc, float* __restrict__ out)
{
    out[0] = __builtin_amdgcn_sqrtf(acc[0]) * 0.70710678118654752440f * 0.25f;
}

extern "C" void kernel_launch(void* const* d_in, const int* in_sizes, int n_in,
                              void* d_out, int out_size, void* d_ws, size_t ws_size,
                              hipStream_t stream)
{
    const float* pred = (const float*)d_in[0];
    const float* tgt  = (const float*)d_in[1];
    float* ws  = (float*)d_ws;
    float* out = (float*)d_out;

    float*    norms = ws;             /* 8 floats                          */
    float*    acc   = ws + 8;         /* 1 float                           */
    unsigned* parts = (unsigned*)(ws + 16);     /* 8*nchunk*PPW u32        */

    /* largest chunk count whose parts buffer fits (64 fills 2 blocks/CU) */
    int nchunk = 64;
    while (nchunk > 1) {
        const size_t need = (16 + (size_t)8 * nchunk * PPW) * sizeof(float);
        if (need <= ws_size) break;
        nchunk >>= 1;
    }

    (void)hipMemsetAsync(ws, 0, 9 * sizeof(float), stream);  /* norms+acc */

    hist_mfma<<<8 * nchunk, 256, 0, stream>>>(pred, tgt, parts, norms, nchunk);
    reduce_loss<<<12 * 8192 / 256, 256, 0, stream>>>(parts, norms, acc, nchunk);
    final_k<<<1, 1, 0, stream>>>(acc, out);
}